// Round 9
// baseline (426.512 us; speedup 1.0000x reference)
//
#include <hip/hip_runtime.h>
#include <cstdint>

constexpr int BATCH = 32;
constexpr int DIMC  = 384;
constexpr int NTOK  = 784;
constexpr int KD    = 32;
constexpr int DV    = 128;
constexpr int PERH  = 192;
constexpr int HQKV  = 1536;
constexpr int DHTOT = 1024;
constexpr int NMC   = 25;                 // ceil(784/32) V m-chunks
constexpr int VPB   = NMC * 8 * 512;      // 102400 elems per bh (swizzled V)
constexpr float BNEPS  = 1e-5f;
constexpr float QSCALE = 0.17677669529663687f;  // 1/sqrt(32)
constexpr float LOG2E  = 1.4426950408889634f;

#define DEVFN static __device__ __forceinline__

using f16x8 = __attribute__((ext_vector_type(8))) _Float16;
using f32x4 = __attribute__((ext_vector_type(4))) float;

DEVFN float hswish(float x) {
  float t = fminf(fmaxf(x + 3.0f, 0.0f), 6.0f);
  return x * t * (1.0f / 6.0f);
}
DEVFN uint16_t f2h(float f) { return __builtin_bit_cast(uint16_t, (_Float16)f); }
DEVFN float h2f(uint16_t u) { return (float)__builtin_bit_cast(_Float16, u); }
DEVFN uint32_t pk2h(float a, float b) {   // v_cvt_pkrtz_f16_f32
  return __builtin_bit_cast(uint32_t, __builtin_amdgcn_cvt_pkrtz(a, b));
}

DEVFN void gload16(const void* g, void* l) {
  __builtin_amdgcn_global_load_lds(
      (const __attribute__((address_space(1))) void*)g,
      (__attribute__((address_space(3))) void*)l, 16, 0, 0);
}

// ---------------- P0a: weights fp32 -> fp16
__global__ __launch_bounds__(256) void convert_w(
    const float* __restrict__ qw, const float* __restrict__ pw,
    uint16_t* __restrict__ qwh, uint16_t* __restrict__ pwh)
{
  constexpr int QW4 = (HQKV * DIMC) / 4;
  constexpr int PW4 = (DIMC * DHTOT) / 4;
  int idx = blockIdx.x * 256 + threadIdx.x;
  if (idx < QW4) {
    float4 v = reinterpret_cast<const float4*>(qw)[idx];
    uint2 p;
    p.x = pk2h(v.x, v.y);
    p.y = pk2h(v.z, v.w);
    reinterpret_cast<uint2*>(qwh)[idx] = p;
  } else if (idx < QW4 + PW4) {
    int i2 = idx - QW4;
    float4 v = reinterpret_cast<const float4*>(pw)[i2];
    uint2 p;
    p.x = pk2h(v.x, v.y);
    p.y = pk2h(v.z, v.w);
    reinterpret_cast<uint2*>(pwh)[i2] = p;
  }
}

// ---------------- P0c: bias matrix fp16 [h][n][m]
__global__ __launch_bounds__(256) void bias_build(
    const float* __restrict__ biases, uint16_t* __restrict__ biasH)
{
  const int n = blockIdx.x, h = blockIdx.y;
  const int t = threadIdx.x;
  if (t >= 196) return;
  const int m0 = 4*t;
  const int ri = (n * 2341) >> 16;
  const int rj = n - ri*28;
  const float* bh_ = biases + (size_t)h * NTOK;
  uint16_t o[4];
  #pragma unroll
  for (int r = 0; r < 4; ++r) {
    int m  = m0 + r;
    int im = (m * 2341) >> 16;
    int jm = m - im*28;
    int di = ri - im; di = di < 0 ? -di : di;
    int dj = rj - jm; dj = dj < 0 ? -dj : dj;
    o[r] = f2h(bh_[di*28 + dj]);
  }
  uint2 p;
  p.x = (uint32_t)o[0] | ((uint32_t)o[1] << 16);
  p.y = (uint32_t)o[2] | ((uint32_t)o[3] << 16);
  *reinterpret_cast<uint2*>(biasH + ((size_t)h*NTOK + n)*NTOK + m0) = p;
}

// ---------------- P0b: x [b][384][784] fp32 -> xT [b][784][384] fp16
__global__ __launch_bounds__(256) void transpose_x(
    const float* __restrict__ x, uint16_t* __restrict__ xT)
{
  const int b = blockIdx.z, n0 = blockIdx.x * 32, c0 = blockIdx.y * 32;
  __shared__ float t[32][33];
  const int tx = threadIdx.x & 31, ty = threadIdx.x >> 5;
  const float* xb = x + (size_t)b * DIMC * NTOK;
  #pragma unroll
  for (int k = 0; k < 4; ++k) {
    int c = c0 + ty + 8*k;
    int n = n0 + tx;
    t[ty + 8*k][tx] = (n < NTOK) ? xb[(size_t)c * NTOK + n] : 0.f;
  }
  __syncthreads();
  uint16_t* xTb = xT + (size_t)b * NTOK * DIMC;
  #pragma unroll
  for (int k = 0; k < 4; ++k) {
    int n = n0 + ty + 8*k;
    if (n < NTOK) xTb[(size_t)n * DIMC + c0 + tx] = f2h(t[tx][ty + 8*k]);
  }
}

// ---------------- K1: QKV MFMA GEMM.  Q,K [bh][n][32]; V swizzled Vp.
// grid (13, 12, nb) block 256
__global__ __launch_bounds__(256) void qkv_gemm(
    const uint16_t* __restrict__ wh, const uint16_t* __restrict__ xT,
    const float* __restrict__ gw, const float* __restrict__ bw,
    const float* __restrict__ mw, const float* __restrict__ vw,
    uint16_t* __restrict__ qb, uint16_t* __restrict__ kb, uint16_t* __restrict__ vb)
{
  const int b  = blockIdx.z;
  const int m0 = blockIdx.y * 128;
  const int n0 = blockIdx.x * 64;
  __shared__ __align__(16) uint16_t As[2][128*64];
  __shared__ __align__(16) uint16_t Bs[2][64*64];

  const int tid = threadIdx.x;
  const int w = tid >> 6, l = tid & 63, lg = l >> 4, ln = l & 15;
  const int wr = w >> 1, wc = w & 1;
  const int wbase = tid & 192;
  const uint16_t* xb = xT + (size_t)b * NTOK * DIMC;

  f32x4 acc[4][2];
  #pragma unroll
  for (int mi = 0; mi < 4; ++mi)
    #pragma unroll
    for (int ni = 0; ni < 2; ++ni) acc[mi][ni] = (f32x4){0.f,0.f,0.f,0.f};

  auto stage = [&](int buf, int k0) {
    #pragma unroll
    for (int j = 0; j < 4; ++j) {
      int s = j*256 + tid;
      int row = s >> 3, sl = s & 7;
      int srck = k0 + 8 * (sl ^ (row & 7));
      gload16(wh + (size_t)(m0 + row) * DIMC + srck,
              &As[buf][(j*256 + wbase) * 8]);
    }
    #pragma unroll
    for (int j = 0; j < 2; ++j) {
      int s = j*256 + tid;
      int row = s >> 3, sl = s & 7;
      int nrow = n0 + row; if (nrow > NTOK-1) nrow = NTOK-1;
      int srck = k0 + 8 * (sl ^ (row & 7));
      gload16(xb + (size_t)nrow * DIMC + srck,
              &Bs[buf][(j*256 + wbase) * 8]);
    }
  };

  stage(0, 0);
  int cur = 0;
  for (int k0 = 0; k0 < DIMC; k0 += 64) {
    __syncthreads();
    if (k0 + 64 < DIMC) stage(cur ^ 1, k0 + 64);
    #pragma unroll
    for (int kk = 0; kk < 2; ++kk) {
      f16x8 af[4], bf[2];
      #pragma unroll
      for (int mi = 0; mi < 4; ++mi) {
        int row = 64*wr + 16*mi + ln;
        int slot = (4*kk + lg) ^ (row & 7);
        af[mi] = *reinterpret_cast<const f16x8*>(&As[cur][row*64 + slot*8]);
      }
      #pragma unroll
      for (int ni = 0; ni < 2; ++ni) {
        int row = 32*wc + 16*ni + ln;
        int slot = (4*kk + lg) ^ (row & 7);
        bf[ni] = *reinterpret_cast<const f16x8*>(&Bs[cur][row*64 + slot*8]);
      }
      #pragma unroll
      for (int mi = 0; mi < 4; ++mi)
        #pragma unroll
        for (int ni = 0; ni < 2; ++ni)
          acc[mi][ni] = __builtin_amdgcn_mfma_f32_16x16x32_f16(
              af[mi], bf[ni], acc[mi][ni], 0, 0, 0);
    }
    cur ^= 1;
  }

  #pragma unroll
  for (int mi = 0; mi < 4; ++mi) {
    const int ob = m0 + 64*wr + 16*mi;
    const int h  = ob / PERH;
    const int r0 = ob - h * PERH;
    const int bh = b*8 + h;
    float sc[4], sh[4];
    #pragma unroll
    for (int r = 0; r < 4; ++r) {
      int o = ob + 4*lg + r;
      float s = gw[o] * rsqrtf(vw[o] + BNEPS);
      sc[r] = s; sh[r] = bw[o] - mw[o]*s;
    }
    #pragma unroll
    for (int ni = 0; ni < 2; ++ni) {
      int n = n0 + 32*wc + 16*ni + ln;
      if (n >= NTOK) continue;
      float v4[4];
      #pragma unroll
      for (int r = 0; r < 4; ++r) v4[r] = hswish(acc[mi][ni][r]*sc[r] + sh[r]);
      if (r0 < 2*KD) {
        if (r0 < KD) {
          #pragma unroll
          for (int r = 0; r < 4; ++r) v4[r] *= QSCALE;
        }
        uint16_t* base = (r0 < KD) ? qb : kb;
        int dd = (r0 & 16) + 4*lg;
        uint2 p;
        p.x = pk2h(v4[0], v4[1]);
        p.y = pk2h(v4[2], v4[3]);
        *reinterpret_cast<uint2*>(base + ((size_t)bh*NTOK + n)*KD + dd) = p;
      } else {
        // V swizzled: Vp[bh][mc][dt][lgv][lnv][j]
        const int dv0 = r0 - 2*KD;
        const int mc = n >> 5, mm = n & 31;
        const int lgv = mm >> 3, jj = mm & 7;
        uint16_t* vblk = vb + (size_t)bh*VPB + ((size_t)mc*8)*512 + lgv*128 + jj;
        #pragma unroll
        for (int r = 0; r < 4; ++r) {
          int dv = dv0 + 4*lg + r;
          int dt = dv >> 4, lnv = dv & 15;
          vblk[(size_t)dt*512 + lnv*8] = f2h(v4[r]);
        }
      }
    }
  }
}

// ---------------- K2: MFMA flash attention, 32 q-rows/wave, defer-max,
// XCD-local grid: blockIdx.x = bh (x-major dispatch -> XCD = h), y = tile grp.
// grid (nb*8, 7) block 256; waves with tile>=25 exit.
__global__ __launch_bounds__(256) void attn_kernel(
    const uint16_t* __restrict__ Qb, const uint16_t* __restrict__ Kb,
    const uint16_t* __restrict__ Vb, const uint16_t* __restrict__ biasH,
    uint16_t* __restrict__ a2T)
{
  const int bh = blockIdx.x;
  const int b_ = bh >> 3;
  const int h  = bh & 7;

  __shared__ __align__(16) uint16_t plds[4][2][16][72];

  const int tid = threadIdx.x;
  const int w   = tid >> 6;
  const int l   = tid & 63;
  const int lg  = l >> 4;
  const int ln  = l & 15;

  const int tile = blockIdx.y * 4 + w;
  if (tile >= 25) return;
  const int n0 = tile * 32;
  const int nA = n0 + ln;
  int nBr = n0 + 16 + ln;
  const int nB = (nBr < NTOK) ? nBr : (NTOK-1);

  const uint16_t* Kbase = Kb + (size_t)bh * NTOK * KD;
  const uint16_t* Vbase = Vb + (size_t)bh * VPB;
  const uint16_t* browA = biasH + ((size_t)h * NTOK + nA) * NTOK;
  const uint16_t* browB = biasH + ((size_t)h * NTOK + nB) * NTOK;

  const f16x8 qfA = *reinterpret_cast<const f16x8*>(
      Qb + ((size_t)bh*NTOK + nA)*KD + 8*lg);
  const f16x8 qfB = *reinterpret_cast<const f16x8*>(
      Qb + ((size_t)bh*NTOK + nB)*KD + 8*lg);

  float MA = -1e30f, LA = 0.f, MB = -1e30f, LB = 0.f;
  f32x4 accA[8], accB[8];
  #pragma unroll
  for (int dt = 0; dt < 8; ++dt) {
    accA[dt] = (f32x4){0.f,0.f,0.f,0.f};
    accB[dt] = (f32x4){0.f,0.f,0.f,0.f};
  }

  for (int mb = 0; mb < NTOK; mb += 64) {
    const int rem   = (NTOK - mb) >> 4;
    const int ntile = rem < 4 ? rem : 4;
    const int mc0   = mb >> 5;

    float pA[16], pB[16];
    #pragma unroll
    for (int i = 0; i < 16; ++i) { pA[i] = -1e30f; pB[i] = -1e30f; }

    #pragma unroll
    for (int t = 0; t < 4; ++t) {
      if (t < ntile) {
        f16x8 kf = *reinterpret_cast<const f16x8*>(
            Kbase + (size_t)(mb + 16*t + ln)*KD + 8*lg);
        uint2 ba = *reinterpret_cast<const uint2*>(browA + mb + 16*t + 4*lg);
        uint2 bb = *reinterpret_cast<const uint2*>(browB + mb + 16*t + 4*lg);
        f32x4 cA, cB;
        cA[0] = h2f((uint16_t)(ba.x & 0xffffu)); cA[1] = h2f((uint16_t)(ba.x >> 16));
        cA[2] = h2f((uint16_t)(ba.y & 0xffffu)); cA[3] = h2f((uint16_t)(ba.y >> 16));
        cB[0] = h2f((uint16_t)(bb.x & 0xffffu)); cB[1] = h2f((uint16_t)(bb.x >> 16));
        cB[2] = h2f((uint16_t)(bb.y & 0xffffu)); cB[3] = h2f((uint16_t)(bb.y >> 16));
        f32x4 sA = __builtin_amdgcn_mfma_f32_16x16x32_f16(kf, qfA, cA, 0, 0, 0);
        f32x4 sB = __builtin_amdgcn_mfma_f32_16x16x32_f16(kf, qfB, cB, 0, 0, 0);
        #pragma unroll
        for (int r = 0; r < 4; ++r) { pA[4*t+r] = sA[r]; pB[4*t+r] = sB[r]; }
      }
    }

    // prefetch ks=0 V (shared by both tiles); latency hides under softmax
    f16x8 vf0[8];
    #pragma unroll
    for (int dt = 0; dt < 8; ++dt)
      vf0[dt] = *reinterpret_cast<const f16x8*>(
          Vbase + ((size_t)mc0*8 + dt)*512 + l*8);

    // ---- row max (per ln across lg lanes)
    float mxA = pA[0], mxB = pB[0];
    #pragma unroll
    for (int i = 1; i < 16; ++i) { mxA = fmaxf(mxA, pA[i]); mxB = fmaxf(mxB, pB[i]); }
    mxA = fmaxf(mxA, __shfl_xor(mxA, 16)); mxA = fmaxf(mxA, __shfl_xor(mxA, 32));
    mxB = fmaxf(mxB, __shfl_xor(mxB, 16)); mxB = fmaxf(mxB, __shfl_xor(mxB, 32));

    // ---- defer-max (T13, THR=4): skip rescale when max growth small
    const bool skip = __all((mxA - MA <= 4.0f) & (mxB - MB <= 4.0f));
    float sumA = 0.f, sumB = 0.f;
    if (skip) {
      #pragma unroll
      for (int i = 0; i < 16; ++i) {
        pA[i] = exp2f((pA[i] - MA) * LOG2E); sumA += pA[i];
        pB[i] = exp2f((pB[i] - MB) * LOG2E); sumB += pB[i];
      }
      sumA += __shfl_xor(sumA, 16); sumA += __shfl_xor(sumA, 32);
      sumB += __shfl_xor(sumB, 16); sumB += __shfl_xor(sumB, 32);
      LA += sumA; LB += sumB;
    } else {
      float MnA = fmaxf(MA, mxA), MnB = fmaxf(MB, mxB);
      float alA = exp2f((MA - MnA) * LOG2E), alB = exp2f((MB - MnB) * LOG2E);
      #pragma unroll
      for (int i = 0; i < 16; ++i) {
        pA[i] = exp2f((pA[i] - MnA) * LOG2E); sumA += pA[i];
        pB[i] = exp2f((pB[i] - MnB) * LOG2E); sumB += pB[i];
      }
      sumA += __shfl_xor(sumA, 16); sumA += __shfl_xor(sumA, 32);
      sumB += __shfl_xor(sumB, 16); sumB += __shfl_xor(sumB, 32);
      LA = LA * alA + sumA; MA = MnA;
      LB = LB * alB + sumB; MB = MnB;
      float alA4[4], alB4[4];
      #pragma unroll
      for (int r = 0; r < 4; ++r) {
        alA4[r] = __shfl(alA, 20*lg + r);
        alB4[r] = __shfl(alB, 20*lg + r);
      }
      #pragma unroll
      for (int dt = 0; dt < 8; ++dt) {
        #pragma unroll
        for (int r = 0; r < 4; ++r) { accA[dt][r] *= alA4[r]; accB[dt][r] *= alB4[r]; }
      }
    }

    #pragma unroll
    for (int t = 0; t < 4; ++t) {
      uint2 ka, kb2;
      ka.x  = pk2h(pA[4*t+0], pA[4*t+1]);
      ka.y  = pk2h(pA[4*t+2], pA[4*t+3]);
      kb2.x = pk2h(pB[4*t+0], pB[4*t+1]);
      kb2.y = pk2h(pB[4*t+2], pB[4*t+3]);
      *reinterpret_cast<uint2*>(&plds[w][0][ln][16*t + 4*lg]) = ka;
      *reinterpret_cast<uint2*>(&plds[w][1][ln][16*t + 4*lg]) = kb2;
    }
    // wave-private LDS: compiler-ordered lgkmcnt, no barrier.

    {
      f16x8 pfA = *reinterpret_cast<const f16x8*>(&plds[w][0][ln][8*lg]);
      f16x8 pfB = *reinterpret_cast<const f16x8*>(&plds[w][1][ln][8*lg]);
      __builtin_amdgcn_s_setprio(1);
      #pragma unroll
      for (int dt = 0; dt < 8; ++dt) {
        accA[dt] = __builtin_amdgcn_mfma_f32_16x16x32_f16(pfA, vf0[dt], accA[dt], 0, 0, 0);
        accB[dt] = __builtin_amdgcn_mfma_f32_16x16x32_f16(pfB, vf0[dt], accB[dt], 0, 0, 0);
      }
      __builtin_amdgcn_s_setprio(0);
    }

    if (mb + 32 < NTOK) {
      f16x8 pfA = *reinterpret_cast<const f16x8*>(&plds[w][0][ln][32 + 8*lg]);
      f16x8 pfB = *reinterpret_cast<const f16x8*>(&plds[w][1][ln][32 + 8*lg]);
      f16x8 vf1[8];
      #pragma unroll
      for (int dt = 0; dt < 8; ++dt)
        vf1[dt] = *reinterpret_cast<const f16x8*>(
            Vbase + ((size_t)(mc0+1)*8 + dt)*512 + l*8);
      __builtin_amdgcn_s_setprio(1);
      #pragma unroll
      for (int dt = 0; dt < 8; ++dt) {
        accA[dt] = __builtin_amdgcn_mfma_f32_16x16x32_f16(pfA, vf1[dt], accA[dt], 0, 0, 0);
        accB[dt] = __builtin_amdgcn_mfma_f32_16x16x32_f16(pfB, vf1[dt], accB[dt], 0, 0, 0);
      }
      __builtin_amdgcn_s_setprio(0);
    }
  }

  float liA = 1.0f / LA, liB = 1.0f / LB;
  float liA4[4], liB4[4];
  #pragma unroll
  for (int r = 0; r < 4; ++r) {
    liA4[r] = __shfl(liA, 20*lg + r);
    liB4[r] = __shfl(liB, 20*lg + r);
  }
  #pragma unroll
  for (int r = 0; r < 4; ++r) {
    int rowA = n0 + 4*lg + r;
    #pragma unroll
    for (int dt = 0; dt < 8; ++dt)
      a2T[((size_t)b_*NTOK + rowA)*DHTOT + h*DV + 16*dt + ln] =
          f2h(hswish(accA[dt][r] * liA4[r]));
    int rowB = n0 + 16 + 4*lg + r;
    if (rowB < NTOK) {
      #pragma unroll
      for (int dt = 0; dt < 8; ++dt)
        a2T[((size_t)b_*NTOK + rowB)*DHTOT + h*DV + 16*dt + ln] =
            f2h(hswish(accB[dt][r] * liB4[r]));
    }
  }
}

// ---------------- K3: proj MFMA GEMM. grid (13, 3, nb) block 256
__global__ __launch_bounds__(256) void proj_gemm(
    const uint16_t* __restrict__ wh, const uint16_t* __restrict__ a2T,
    const float* __restrict__ gw, const float* __restrict__ bw,
    const float* __restrict__ mw, const float* __restrict__ vw,
    float* __restrict__ out)
{
  const int b  = blockIdx.z;
  const int m0 = blockIdx.y * 128;
  const int n0 = blockIdx.x * 64;
  __shared__ __align__(16) uint16_t As[2][128*64];
  __shared__ __align__(16) uint16_t Bs[2][64*64];

  const int tid = threadIdx.x;
  const int w = tid >> 6, l = tid & 63, lg = l >> 4, ln = l & 15;
  const int wr = w >> 1, wc = w & 1;
  const int wbase = tid & 192;
  const uint16_t* ab = a2T + (size_t)b * NTOK * DHTOT;

  f32x4 acc[4][2];
  #pragma unroll
  for (int mi = 0; mi < 4; ++mi)
    #pragma unroll
    for (int ni = 0; ni < 2; ++ni) acc[mi][ni] = (f32x4){0.f,0.f,0.f,0.f};

  auto stage = [&](int buf, int k0) {
    #pragma unroll
    for (int j = 0; j < 4; ++j) {
      int s = j*256 + tid;
      int row = s >> 3, sl = s & 7;
      int srck = k0 + 8 * (sl ^ (row & 7));
      gload16(wh + (size_t)(m0 + row) * DHTOT + srck,
              &As[buf][(j*256 + wbase) * 8]);
    }
    #pragma unroll
    for (int j = 0; j < 2; ++j) {
      int s = j*256 + tid;
      int row = s >> 3, sl = s & 7;
      int nrow = n0 + row; if (nrow > NTOK-1) nrow = NTOK-1;
      int srck = k0 + 8 * (sl ^ (row & 7));
      gload16(ab + (size_t)nrow * DHTOT + srck,
              &Bs[buf][(j*256 + wbase) * 8]);
    }
  };

  stage(0, 0);
  int cur = 0;
  for (int k0 = 0; k0 < DHTOT; k0 += 64) {
    __syncthreads();
    if (k0 + 64 < DHTOT) stage(cur ^ 1, k0 + 64);
    #pragma unroll
    for (int kk = 0; kk < 2; ++kk) {
      f16x8 af[4], bf[2];
      #pragma unroll
      for (int mi = 0; mi < 4; ++mi) {
        int row = 64*wr + 16*mi + ln;
        int slot = (4*kk + lg) ^ (row & 7);
        af[mi] = *reinterpret_cast<const f16x8*>(&As[cur][row*64 + slot*8]);
      }
      #pragma unroll
      for (int ni = 0; ni < 2; ++ni) {
        int row = 32*wc + 16*ni + ln;
        int slot = (4*kk + lg) ^ (row & 7);
        bf[ni] = *reinterpret_cast<const f16x8*>(&Bs[cur][row*64 + slot*8]);
      }
      #pragma unroll
      for (int mi = 0; mi < 4; ++mi)
        #pragma unroll
        for (int ni = 0; ni < 2; ++ni)
          acc[mi][ni] = __builtin_amdgcn_mfma_f32_16x16x32_f16(
              af[mi], bf[ni], acc[mi][ni], 0, 0, 0);
    }
    cur ^= 1;
  }

  #pragma unroll
  for (int mi = 0; mi < 4; ++mi) {
    float sc[4], sh[4];
    #pragma unroll
    for (int r = 0; r < 4; ++r) {
      int o = m0 + 64*wr + 16*mi + 4*lg + r;
      float s = gw[o] * rsqrtf(vw[o] + BNEPS);
      sc[r] = s; sh[r] = bw[o] - mw[o]*s;
    }
    #pragma unroll
    for (int ni = 0; ni < 2; ++ni) {
      int n = n0 + 32*wc + 16*ni + ln;
      if (n >= NTOK) continue;
      #pragma unroll
      for (int r = 0; r < 4; ++r) {
        int o = m0 + 64*wr + 16*mi + 4*lg + r;
        out[((size_t)b*DIMC + o)*NTOK + n] = hswish(acc[mi][ni][r]*sc[r] + sh[r]);
      }
    }
  }
}

extern "C" void kernel_launch(void* const* d_in, const int* in_sizes, int n_in,
                              void* d_out, int out_size, void* d_ws, size_t ws_size,
                              hipStream_t stream)
{
  const float* x  = (const float*)d_in[0];
  const float* qw = (const float*)d_in[1];
  const float* qg = (const float*)d_in[2];
  const float* qb_ = (const float*)d_in[3];
  const float* qm = (const float*)d_in[4];
  const float* qv = (const float*)d_in[5];
  const float* ab = (const float*)d_in[6];
  const float* pw = (const float*)d_in[7];
  const float* pg = (const float*)d_in[8];
  const float* pb = (const float*)d_in[9];
  const float* pm = (const float*)d_in[10];
  const float* pv = (const float*)d_in[11];
  float* out = (float*)d_out;

  uint16_t* qwh   = (uint16_t*)d_ws;
  uint16_t* pwh   = qwh + (size_t)HQKV * DIMC;
  uint16_t* biasH = pwh + (size_t)DIMC * DHTOT;
  uint16_t* dyn   = biasH + (size_t)8 * NTOK * NTOK;
  const size_t fixed_bytes =
      ((size_t)HQKV*DIMC + (size_t)DIMC*DHTOT + (size_t)8*NTOK*NTOK) * 2;

  const size_t XT_B = (size_t)NTOK * DIMC;
  const size_t QK_B = (size_t)8 * NTOK * KD;
  const size_t V_B  = (size_t)8 * VPB;          // swizzled V, padded
  const size_t A2_B = (size_t)NTOK * DHTOT;
  const size_t PER_B = XT_B + 2*QK_B + V_B + A2_B;

  size_t avail = (ws_size > fixed_bytes) ? (ws_size - fixed_bytes) : 0;
  int nb = (int)(avail / (PER_B * 2));
  if (nb > BATCH) nb = BATCH;
  if (nb < 1) nb = 1;

  uint16_t* xTb  = dyn;
  uint16_t* qbuf = xTb  + (size_t)nb * XT_B;
  uint16_t* kbuf = qbuf + (size_t)nb * QK_B;
  uint16_t* vbuf = kbuf + (size_t)nb * QK_B;
  uint16_t* a2   = vbuf + (size_t)nb * V_B;

  convert_w<<<960, 256, 0, stream>>>(qw, pw, qwh, pwh);
  bias_build<<<dim3(NTOK, 8), 256, 0, stream>>>(ab, biasH);

  for (int b0 = 0; b0 < BATCH; b0 += nb) {
    int cb = BATCH - b0; if (cb > nb) cb = nb;
    const float* xb = x + (size_t)b0 * DIMC * NTOK;
    float* ob = out + (size_t)b0 * DIMC * NTOK;

    transpose_x<<<dim3(25, 12, cb), 256, 0, stream>>>(xb, xTb);
    qkv_gemm<<<dim3(13, 12, cb), 256, 0, stream>>>(qwh, xTb, qg, qb_, qm, qv,
                                                   qbuf, kbuf, vbuf);
    attn_kernel<<<dim3(cb * 8, 7), 256, 0, stream>>>(qbuf, kbuf, vbuf, biasH, a2);
    proj_gemm<<<dim3(13, 3, cb), 256, 0, stream>>>(pwh, a2, pg, pb, pm, pv, ob);
  }
}

// Round 10
// 309.746 us; speedup vs baseline: 1.3770x; 1.3770x over previous
//
#include <hip/hip_runtime.h>
#include <cstdint>

constexpr int BATCH = 32;
constexpr int DIMC  = 384;
constexpr int NTOK  = 784;
constexpr int KD    = 32;
constexpr int DV    = 128;
constexpr int PERH  = 192;
constexpr int HQKV  = 1536;
constexpr int DHTOT = 1024;
constexpr int NMC   = 25;                 // ceil(784/32) V m-chunks
constexpr int VPB   = NMC * 8 * 512;      // 102400 elems per bh (swizzled V)
constexpr float BNEPS  = 1e-5f;
constexpr float LOG2E  = 1.4426950408889634f;
constexpr float QSCL2  = 0.17677669529663687f * LOG2E;  // 1/sqrt(32) * log2(e)

#define DEVFN static __device__ __forceinline__

using f16x8 = __attribute__((ext_vector_type(8))) _Float16;
using f32x4 = __attribute__((ext_vector_type(4))) float;

DEVFN float hswish(float x) {
  float t = fminf(fmaxf(x + 3.0f, 0.0f), 6.0f);
  return x * t * (1.0f / 6.0f);
}
DEVFN uint16_t f2h(float f) { return __builtin_bit_cast(uint16_t, (_Float16)f); }
DEVFN float h2f(uint16_t u) { return (float)__builtin_bit_cast(_Float16, u); }
DEVFN uint32_t pk2h(float a, float b) {   // v_cvt_pkrtz_f16_f32
  return __builtin_bit_cast(uint32_t, __builtin_amdgcn_cvt_pkrtz(a, b));
}

DEVFN void gload16(const void* g, void* l) {
  __builtin_amdgcn_global_load_lds(
      (const __attribute__((address_space(1))) void*)g,
      (__attribute__((address_space(3))) void*)l, 16, 0, 0);
}

// ---------------- P0a: weights fp32 -> fp16
__global__ __launch_bounds__(256) void convert_w(
    const float* __restrict__ qw, const float* __restrict__ pw,
    uint16_t* __restrict__ qwh, uint16_t* __restrict__ pwh)
{
  constexpr int QW4 = (HQKV * DIMC) / 4;
  constexpr int PW4 = (DIMC * DHTOT) / 4;
  int idx = blockIdx.x * 256 + threadIdx.x;
  if (idx < QW4) {
    float4 v = reinterpret_cast<const float4*>(qw)[idx];
    uint2 p;
    p.x = pk2h(v.x, v.y);
    p.y = pk2h(v.z, v.w);
    reinterpret_cast<uint2*>(qwh)[idx] = p;
  } else if (idx < QW4 + PW4) {
    int i2 = idx - QW4;
    float4 v = reinterpret_cast<const float4*>(pw)[i2];
    uint2 p;
    p.x = pk2h(v.x, v.y);
    p.y = pk2h(v.z, v.w);
    reinterpret_cast<uint2*>(pwh)[i2] = p;
  }
}

// ---------------- P0c: bias matrix fp16 [h][n][m], pre-scaled by log2(e)
__global__ __launch_bounds__(256) void bias_build(
    const float* __restrict__ biases, uint16_t* __restrict__ biasH)
{
  const int n = blockIdx.x, h = blockIdx.y;
  const int t = threadIdx.x;
  if (t >= 196) return;
  const int m0 = 4*t;
  const int ri = (n * 2341) >> 16;
  const int rj = n - ri*28;
  const float* bh_ = biases + (size_t)h * NTOK;
  uint16_t o[4];
  #pragma unroll
  for (int r = 0; r < 4; ++r) {
    int m  = m0 + r;
    int im = (m * 2341) >> 16;
    int jm = m - im*28;
    int di = ri - im; di = di < 0 ? -di : di;
    int dj = rj - jm; dj = dj < 0 ? -dj : dj;
    o[r] = f2h(bh_[di*28 + dj] * LOG2E);
  }
  uint2 p;
  p.x = (uint32_t)o[0] | ((uint32_t)o[1] << 16);
  p.y = (uint32_t)o[2] | ((uint32_t)o[3] << 16);
  *reinterpret_cast<uint2*>(biasH + ((size_t)h*NTOK + n)*NTOK + m0) = p;
}

// ---------------- P0b: x [b][384][784] fp32 -> xT [b][784][384] fp16
__global__ __launch_bounds__(256) void transpose_x(
    const float* __restrict__ x, uint16_t* __restrict__ xT)
{
  const int b = blockIdx.z, n0 = blockIdx.x * 32, c0 = blockIdx.y * 32;
  __shared__ float t[32][33];
  const int tx = threadIdx.x & 31, ty = threadIdx.x >> 5;
  const float* xb = x + (size_t)b * DIMC * NTOK;
  #pragma unroll
  for (int k = 0; k < 4; ++k) {
    int c = c0 + ty + 8*k;
    int n = n0 + tx;
    t[ty + 8*k][tx] = (n < NTOK) ? xb[(size_t)c * NTOK + n] : 0.f;
  }
  __syncthreads();
  uint16_t* xTb = xT + (size_t)b * NTOK * DIMC;
  #pragma unroll
  for (int k = 0; k < 4; ++k) {
    int n = n0 + ty + 8*k;
    if (n < NTOK) xTb[(size_t)n * DIMC + c0 + tx] = f2h(t[tx][ty + 8*k]);
  }
}

// ---------------- K1: QKV MFMA GEMM.  Q,K [bh][n][32]; V swizzled Vp.
// q pre-scaled by (1/sqrt(32))*log2(e)  -> scores natively in log2 domain.
// grid (13, 12, nb) block 256
__global__ __launch_bounds__(256) void qkv_gemm(
    const uint16_t* __restrict__ wh, const uint16_t* __restrict__ xT,
    const float* __restrict__ gw, const float* __restrict__ bw,
    const float* __restrict__ mw, const float* __restrict__ vw,
    uint16_t* __restrict__ qb, uint16_t* __restrict__ kb, uint16_t* __restrict__ vb)
{
  const int b  = blockIdx.z;
  const int m0 = blockIdx.y * 128;
  const int n0 = blockIdx.x * 64;
  __shared__ __align__(16) uint16_t As[2][128*64];
  __shared__ __align__(16) uint16_t Bs[2][64*64];

  const int tid = threadIdx.x;
  const int w = tid >> 6, l = tid & 63, lg = l >> 4, ln = l & 15;
  const int wr = w >> 1, wc = w & 1;
  const int wbase = tid & 192;
  const uint16_t* xb = xT + (size_t)b * NTOK * DIMC;

  f32x4 acc[4][2];
  #pragma unroll
  for (int mi = 0; mi < 4; ++mi)
    #pragma unroll
    for (int ni = 0; ni < 2; ++ni) acc[mi][ni] = (f32x4){0.f,0.f,0.f,0.f};

  auto stage = [&](int buf, int k0) {
    #pragma unroll
    for (int j = 0; j < 4; ++j) {
      int s = j*256 + tid;
      int row = s >> 3, sl = s & 7;
      int srck = k0 + 8 * (sl ^ (row & 7));
      gload16(wh + (size_t)(m0 + row) * DIMC + srck,
              &As[buf][(j*256 + wbase) * 8]);
    }
    #pragma unroll
    for (int j = 0; j < 2; ++j) {
      int s = j*256 + tid;
      int row = s >> 3, sl = s & 7;
      int nrow = n0 + row; if (nrow > NTOK-1) nrow = NTOK-1;
      int srck = k0 + 8 * (sl ^ (row & 7));
      gload16(xb + (size_t)nrow * DIMC + srck,
              &Bs[buf][(j*256 + wbase) * 8]);
    }
  };

  stage(0, 0);
  int cur = 0;
  for (int k0 = 0; k0 < DIMC; k0 += 64) {
    __syncthreads();
    if (k0 + 64 < DIMC) stage(cur ^ 1, k0 + 64);
    #pragma unroll
    for (int kk = 0; kk < 2; ++kk) {
      f16x8 af[4], bf[2];
      #pragma unroll
      for (int mi = 0; mi < 4; ++mi) {
        int row = 64*wr + 16*mi + ln;
        int slot = (4*kk + lg) ^ (row & 7);
        af[mi] = *reinterpret_cast<const f16x8*>(&As[cur][row*64 + slot*8]);
      }
      #pragma unroll
      for (int ni = 0; ni < 2; ++ni) {
        int row = 32*wc + 16*ni + ln;
        int slot = (4*kk + lg) ^ (row & 7);
        bf[ni] = *reinterpret_cast<const f16x8*>(&Bs[cur][row*64 + slot*8]);
      }
      #pragma unroll
      for (int mi = 0; mi < 4; ++mi)
        #pragma unroll
        for (int ni = 0; ni < 2; ++ni)
          acc[mi][ni] = __builtin_amdgcn_mfma_f32_16x16x32_f16(
              af[mi], bf[ni], acc[mi][ni], 0, 0, 0);
    }
    cur ^= 1;
  }

  #pragma unroll
  for (int mi = 0; mi < 4; ++mi) {
    const int ob = m0 + 64*wr + 16*mi;
    const int h  = ob / PERH;
    const int r0 = ob - h * PERH;
    const int bh = b*8 + h;
    float sc[4], sh[4];
    #pragma unroll
    for (int r = 0; r < 4; ++r) {
      int o = ob + 4*lg + r;
      float s = gw[o] * rsqrtf(vw[o] + BNEPS);
      sc[r] = s; sh[r] = bw[o] - mw[o]*s;
    }
    #pragma unroll
    for (int ni = 0; ni < 2; ++ni) {
      int n = n0 + 32*wc + 16*ni + ln;
      if (n >= NTOK) continue;
      float v4[4];
      #pragma unroll
      for (int r = 0; r < 4; ++r) v4[r] = hswish(acc[mi][ni][r]*sc[r] + sh[r]);
      if (r0 < 2*KD) {
        if (r0 < KD) {
          #pragma unroll
          for (int r = 0; r < 4; ++r) v4[r] *= QSCL2;
        }
        uint16_t* base = (r0 < KD) ? qb : kb;
        int dd = (r0 & 16) + 4*lg;
        uint2 p;
        p.x = pk2h(v4[0], v4[1]);
        p.y = pk2h(v4[2], v4[3]);
        *reinterpret_cast<uint2*>(base + ((size_t)bh*NTOK + n)*KD + dd) = p;
      } else {
        // V swizzled: Vp[bh][mc][dt][lgv][lnv][j]
        const int dv0 = r0 - 2*KD;
        const int mc = n >> 5, mm = n & 31;
        const int lgv = mm >> 3, jj = mm & 7;
        uint16_t* vblk = vb + (size_t)bh*VPB + ((size_t)mc*8)*512 + lgv*128 + jj;
        #pragma unroll
        for (int r = 0; r < 4; ++r) {
          int dv = dv0 + 4*lg + r;
          int dt = dv >> 4, lnv = dv & 15;
          vblk[(size_t)dt*512 + lnv*8] = f2h(v4[r]);
        }
      }
    }
  }
}

// ---------------- K2: MFMA flash attention, 32 q-rows/wave, log2-domain scores.
// XCD-local grid: blockIdx.x = bh, y = tile grp.  grid (nb*8, 7) block 256.
__global__ __launch_bounds__(256) void attn_kernel(
    const uint16_t* __restrict__ Qb, const uint16_t* __restrict__ Kb,
    const uint16_t* __restrict__ Vb, const uint16_t* __restrict__ biasH,
    uint16_t* __restrict__ a2T)
{
  const int bh = blockIdx.x;
  const int b_ = bh >> 3;
  const int h  = bh & 7;

  __shared__ __align__(16) uint16_t plds[4][2][16][72];

  const int tid = threadIdx.x;
  const int w   = tid >> 6;
  const int l   = tid & 63;
  const int lg  = l >> 4;
  const int ln  = l & 15;

  const int tile = blockIdx.y * 4 + w;
  if (tile >= 25) return;
  const int n0 = tile * 32;
  const int nA = n0 + ln;
  int nBr = n0 + 16 + ln;
  const int nB = (nBr < NTOK) ? nBr : (NTOK-1);

  const uint16_t* Kbase = Kb + (size_t)bh * NTOK * KD;
  const uint16_t* Vbase = Vb + (size_t)bh * VPB;
  const uint16_t* browA = biasH + ((size_t)h * NTOK + nA) * NTOK;
  const uint16_t* browB = biasH + ((size_t)h * NTOK + nB) * NTOK;

  const f16x8 qfA = *reinterpret_cast<const f16x8*>(
      Qb + ((size_t)bh*NTOK + nA)*KD + 8*lg);
  const f16x8 qfB = *reinterpret_cast<const f16x8*>(
      Qb + ((size_t)bh*NTOK + nB)*KD + 8*lg);

  float MA = -1e30f, LA = 0.f, MB = -1e30f, LB = 0.f;
  f32x4 accA[8], accB[8];
  #pragma unroll
  for (int dt = 0; dt < 8; ++dt) {
    accA[dt] = (f32x4){0.f,0.f,0.f,0.f};
    accB[dt] = (f32x4){0.f,0.f,0.f,0.f};
  }

  for (int mb = 0; mb < NTOK; mb += 64) {
    const int rem   = (NTOK - mb) >> 4;
    const int ntile = rem < 4 ? rem : 4;
    const int mc0   = mb >> 5;

    float pA[16], pB[16];
    #pragma unroll
    for (int i = 0; i < 16; ++i) { pA[i] = -1e30f; pB[i] = -1e30f; }

    #pragma unroll
    for (int t = 0; t < 4; ++t) {
      if (t < ntile) {
        f16x8 kf = *reinterpret_cast<const f16x8*>(
            Kbase + (size_t)(mb + 16*t + ln)*KD + 8*lg);
        uint2 ba = *reinterpret_cast<const uint2*>(browA + mb + 16*t + 4*lg);
        uint2 bb = *reinterpret_cast<const uint2*>(browB + mb + 16*t + 4*lg);
        f32x4 cA, cB;
        cA[0] = h2f((uint16_t)(ba.x & 0xffffu)); cA[1] = h2f((uint16_t)(ba.x >> 16));
        cA[2] = h2f((uint16_t)(ba.y & 0xffffu)); cA[3] = h2f((uint16_t)(ba.y >> 16));
        cB[0] = h2f((uint16_t)(bb.x & 0xffffu)); cB[1] = h2f((uint16_t)(bb.x >> 16));
        cB[2] = h2f((uint16_t)(bb.y & 0xffffu)); cB[3] = h2f((uint16_t)(bb.y >> 16));
        f32x4 sA = __builtin_amdgcn_mfma_f32_16x16x32_f16(kf, qfA, cA, 0, 0, 0);
        f32x4 sB = __builtin_amdgcn_mfma_f32_16x16x32_f16(kf, qfB, cB, 0, 0, 0);
        #pragma unroll
        for (int r = 0; r < 4; ++r) { pA[4*t+r] = sA[r]; pB[4*t+r] = sB[r]; }
      }
    }

    // prefetch ks=0 V (shared by both tiles); latency hides under softmax
    f16x8 vf0[8];
    #pragma unroll
    for (int dt = 0; dt < 8; ++dt)
      vf0[dt] = *reinterpret_cast<const f16x8*>(
          Vbase + ((size_t)mc0*8 + dt)*512 + l*8);

    // ---- softmax A and B (log2 domain: no LOG2E multiplies)
    float mxA = pA[0], mxB = pB[0];
    #pragma unroll
    for (int i = 1; i < 16; ++i) { mxA = fmaxf(mxA, pA[i]); mxB = fmaxf(mxB, pB[i]); }
    mxA = fmaxf(mxA, __shfl_xor(mxA, 16)); mxA = fmaxf(mxA, __shfl_xor(mxA, 32));
    mxB = fmaxf(mxB, __shfl_xor(mxB, 16)); mxB = fmaxf(mxB, __shfl_xor(mxB, 32));

    float MnA = fmaxf(MA, mxA), MnB = fmaxf(MB, mxB);
    float alA = exp2f(MA - MnA), alB = exp2f(MB - MnB);
    float sumA = 0.f, sumB = 0.f;
    #pragma unroll
    for (int i = 0; i < 16; ++i) {
      pA[i] = exp2f(pA[i] - MnA); sumA += pA[i];
      pB[i] = exp2f(pB[i] - MnB); sumB += pB[i];
    }
    sumA += __shfl_xor(sumA, 16); sumA += __shfl_xor(sumA, 32);
    sumB += __shfl_xor(sumB, 16); sumB += __shfl_xor(sumB, 32);
    LA = LA * alA + sumA; MA = MnA;
    LB = LB * alB + sumB; MB = MnB;

    float alA4[4], alB4[4];
    #pragma unroll
    for (int r = 0; r < 4; ++r) {
      alA4[r] = __shfl(alA, 20*lg + r);
      alB4[r] = __shfl(alB, 20*lg + r);
    }
    #pragma unroll
    for (int dt = 0; dt < 8; ++dt) {
      #pragma unroll
      for (int r = 0; r < 4; ++r) { accA[dt][r] *= alA4[r]; accB[dt][r] *= alB4[r]; }
    }

    #pragma unroll
    for (int t = 0; t < 4; ++t) {
      uint2 ka, kb2;
      ka.x  = pk2h(pA[4*t+0], pA[4*t+1]);
      ka.y  = pk2h(pA[4*t+2], pA[4*t+3]);
      kb2.x = pk2h(pB[4*t+0], pB[4*t+1]);
      kb2.y = pk2h(pB[4*t+2], pB[4*t+3]);
      *reinterpret_cast<uint2*>(&plds[w][0][ln][16*t + 4*lg]) = ka;
      *reinterpret_cast<uint2*>(&plds[w][1][ln][16*t + 4*lg]) = kb2;
    }
    // wave-private LDS: compiler-ordered lgkmcnt, no barrier.

    {
      f16x8 pfA = *reinterpret_cast<const f16x8*>(&plds[w][0][ln][8*lg]);
      f16x8 pfB = *reinterpret_cast<const f16x8*>(&plds[w][1][ln][8*lg]);
      __builtin_amdgcn_s_setprio(1);
      #pragma unroll
      for (int dt = 0; dt < 8; ++dt) {
        accA[dt] = __builtin_amdgcn_mfma_f32_16x16x32_f16(pfA, vf0[dt], accA[dt], 0, 0, 0);
        accB[dt] = __builtin_amdgcn_mfma_f32_16x16x32_f16(pfB, vf0[dt], accB[dt], 0, 0, 0);
      }
      __builtin_amdgcn_s_setprio(0);
    }

    if (mb + 32 < NTOK) {
      f16x8 pfA = *reinterpret_cast<const f16x8*>(&plds[w][0][ln][32 + 8*lg]);
      f16x8 pfB = *reinterpret_cast<const f16x8*>(&plds[w][1][ln][32 + 8*lg]);
      f16x8 vf1[8];
      #pragma unroll
      for (int dt = 0; dt < 8; ++dt)
        vf1[dt] = *reinterpret_cast<const f16x8*>(
            Vbase + ((size_t)(mc0+1)*8 + dt)*512 + l*8);
      __builtin_amdgcn_s_setprio(1);
      #pragma unroll
      for (int dt = 0; dt < 8; ++dt) {
        accA[dt] = __builtin_amdgcn_mfma_f32_16x16x32_f16(pfA, vf1[dt], accA[dt], 0, 0, 0);
        accB[dt] = __builtin_amdgcn_mfma_f32_16x16x32_f16(pfB, vf1[dt], accB[dt], 0, 0, 0);
      }
      __builtin_amdgcn_s_setprio(0);
    }
  }

  float liA = 1.0f / LA, liB = 1.0f / LB;
  float liA4[4], liB4[4];
  #pragma unroll
  for (int r = 0; r < 4; ++r) {
    liA4[r] = __shfl(liA, 20*lg + r);
    liB4[r] = __shfl(liB, 20*lg + r);
  }
  #pragma unroll
  for (int r = 0; r < 4; ++r) {
    int rowA = n0 + 4*lg + r;
    #pragma unroll
    for (int dt = 0; dt < 8; ++dt)
      a2T[((size_t)b_*NTOK + rowA)*DHTOT + h*DV + 16*dt + ln] =
          f2h(hswish(accA[dt][r] * liA4[r]));
    int rowB = n0 + 16 + 4*lg + r;
    if (rowB < NTOK) {
      #pragma unroll
      for (int dt = 0; dt < 8; ++dt)
        a2T[((size_t)b_*NTOK + rowB)*DHTOT + h*DV + 16*dt + ln] =
            f2h(hswish(accB[dt][r] * liB4[r]));
    }
  }
}

// ---------------- K3: proj MFMA GEMM. grid (13, 3, nb) block 256
__global__ __launch_bounds__(256) void proj_gemm(
    const uint16_t* __restrict__ wh, const uint16_t* __restrict__ a2T,
    const float* __restrict__ gw, const float* __restrict__ bw,
    const float* __restrict__ mw, const float* __restrict__ vw,
    float* __restrict__ out)
{
  const int b  = blockIdx.z;
  const int m0 = blockIdx.y * 128;
  const int n0 = blockIdx.x * 64;
  __shared__ __align__(16) uint16_t As[2][128*64];
  __shared__ __align__(16) uint16_t Bs[2][64*64];

  const int tid = threadIdx.x;
  const int w = tid >> 6, l = tid & 63, lg = l >> 4, ln = l & 15;
  const int wr = w >> 1, wc = w & 1;
  const int wbase = tid & 192;
  const uint16_t* ab = a2T + (size_t)b * NTOK * DHTOT;

  f32x4 acc[4][2];
  #pragma unroll
  for (int mi = 0; mi < 4; ++mi)
    #pragma unroll
    for (int ni = 0; ni < 2; ++ni) acc[mi][ni] = (f32x4){0.f,0.f,0.f,0.f};

  auto stage = [&](int buf, int k0) {
    #pragma unroll
    for (int j = 0; j < 4; ++j) {
      int s = j*256 + tid;
      int row = s >> 3, sl = s & 7;
      int srck = k0 + 8 * (sl ^ (row & 7));
      gload16(wh + (size_t)(m0 + row) * DHTOT + srck,
              &As[buf][(j*256 + wbase) * 8]);
    }
    #pragma unroll
    for (int j = 0; j < 2; ++j) {
      int s = j*256 + tid;
      int row = s >> 3, sl = s & 7;
      int nrow = n0 + row; if (nrow > NTOK-1) nrow = NTOK-1;
      int srck = k0 + 8 * (sl ^ (row & 7));
      gload16(ab + (size_t)nrow * DHTOT + srck,
              &Bs[buf][(j*256 + wbase) * 8]);
    }
  };

  stage(0, 0);
  int cur = 0;
  for (int k0 = 0; k0 < DHTOT; k0 += 64) {
    __syncthreads();
    if (k0 + 64 < DHTOT) stage(cur ^ 1, k0 + 64);
    #pragma unroll
    for (int kk = 0; kk < 2; ++kk) {
      f16x8 af[4], bf[2];
      #pragma unroll
      for (int mi = 0; mi < 4; ++mi) {
        int row = 64*wr + 16*mi + ln;
        int slot = (4*kk + lg) ^ (row & 7);
        af[mi] = *reinterpret_cast<const f16x8*>(&As[cur][row*64 + slot*8]);
      }
      #pragma unroll
      for (int ni = 0; ni < 2; ++ni) {
        int row = 32*wc + 16*ni + ln;
        int slot = (4*kk + lg) ^ (row & 7);
        bf[ni] = *reinterpret_cast<const f16x8*>(&Bs[cur][row*64 + slot*8]);
      }
      #pragma unroll
      for (int mi = 0; mi < 4; ++mi)
        #pragma unroll
        for (int ni = 0; ni < 2; ++ni)
          acc[mi][ni] = __builtin_amdgcn_mfma_f32_16x16x32_f16(
              af[mi], bf[ni], acc[mi][ni], 0, 0, 0);
    }
    cur ^= 1;
  }

  #pragma unroll
  for (int mi = 0; mi < 4; ++mi) {
    float sc[4], sh[4];
    #pragma unroll
    for (int r = 0; r < 4; ++r) {
      int o = m0 + 64*wr + 16*mi + 4*lg + r;
      float s = gw[o] * rsqrtf(vw[o] + BNEPS);
      sc[r] = s; sh[r] = bw[o] - mw[o]*s;
    }
    #pragma unroll
    for (int ni = 0; ni < 2; ++ni) {
      int n = n0 + 32*wc + 16*ni + ln;
      if (n >= NTOK) continue;
      #pragma unroll
      for (int r = 0; r < 4; ++r) {
        int o = m0 + 64*wr + 16*mi + 4*lg + r;
        out[((size_t)b*DIMC + o)*NTOK + n] = hswish(acc[mi][ni][r]*sc[r] + sh[r]);
      }
    }
  }
}

extern "C" void kernel_launch(void* const* d_in, const int* in_sizes, int n_in,
                              void* d_out, int out_size, void* d_ws, size_t ws_size,
                              hipStream_t stream)
{
  const float* x  = (const float*)d_in[0];
  const float* qw = (const float*)d_in[1];
  const float* qg = (const float*)d_in[2];
  const float* qb_ = (const float*)d_in[3];
  const float* qm = (const float*)d_in[4];
  const float* qv = (const float*)d_in[5];
  const float* ab = (const float*)d_in[6];
  const float* pw = (const float*)d_in[7];
  const float* pg = (const float*)d_in[8];
  const float* pb = (const float*)d_in[9];
  const float* pm = (const float*)d_in[10];
  const float* pv = (const float*)d_in[11];
  float* out = (float*)d_out;

  uint16_t* qwh   = (uint16_t*)d_ws;
  uint16_t* pwh   = qwh + (size_t)HQKV * DIMC;
  uint16_t* biasH = pwh + (size_t)DIMC * DHTOT;
  uint16_t* dyn   = biasH + (size_t)8 * NTOK * NTOK;
  const size_t fixed_bytes =
      ((size_t)HQKV*DIMC + (size_t)DIMC*DHTOT + (size_t)8*NTOK*NTOK) * 2;

  const size_t XT_B = (size_t)NTOK * DIMC;
  const size_t QK_B = (size_t)8 * NTOK * KD;
  const size_t V_B  = (size_t)8 * VPB;          // swizzled V, padded
  const size_t A2_B = (size_t)NTOK * DHTOT;
  const size_t PER_B = XT_B + 2*QK_B + V_B + A2_B;

  size_t avail = (ws_size > fixed_bytes) ? (ws_size - fixed_bytes) : 0;
  int nb = (int)(avail / (PER_B * 2));
  if (nb > BATCH) nb = BATCH;
  if (nb < 1) nb = 1;

  uint16_t* xTb  = dyn;
  uint16_t* qbuf = xTb  + (size_t)nb * XT_B;
  uint16_t* kbuf = qbuf + (size_t)nb * QK_B;
  uint16_t* vbuf = kbuf + (size_t)nb * QK_B;
  uint16_t* a2   = vbuf + (size_t)nb * V_B;

  convert_w<<<960, 256, 0, stream>>>(qw, pw, qwh, pwh);
  bias_build<<<dim3(NTOK, 8), 256, 0, stream>>>(ab, biasH);

  for (int b0 = 0; b0 < BATCH; b0 += nb) {
    int cb = BATCH - b0; if (cb > nb) cb = nb;
    const float* xb = x + (size_t)b0 * DIMC * NTOK;
    float* ob = out + (size_t)b0 * DIMC * NTOK;

    transpose_x<<<dim3(25, 12, cb), 256, 0, stream>>>(xb, xTb);
    qkv_gemm<<<dim3(13, 12, cb), 256, 0, stream>>>(qwh, xTb, qg, qb_, qm, qv,
                                                   qbuf, kbuf, vbuf);
    attn_kernel<<<dim3(cb * 8, 7), 256, 0, stream>>>(qbuf, kbuf, vbuf, biasH, a2);
    proj_gemm<<<dim3(13, 3, cb), 256, 0, stream>>>(pwh, a2, pg, pb, pm, pv, ob);
  }
}